// Round 8
// baseline (632.134 us; speedup 1.0000x reference)
//
#include <hip/hip_runtime.h>
#include <hip/hip_cooperative_groups.h>

namespace cg = cooperative_groups;

#define CH    256
#define MEM   684
#define POSN  128
#define NEGN  512
#define CLS   60
#define ROWS  41040
#define BATCHN 512

#define T1F 0.09375f   // hard-neg pre-filter (c > T1), ~6.7% pass
#define T0F 0.03125f   // rand pre-filter (r < T0), ~3.1% pass
#define CAPCL 4096     // per-row c-candidate cap (E~2700)
#define CAPRL 2048     // per-row r-candidate cap (E~1261)
#define CSTG  32       // per-block-row LDS stage cap per gemm tile (E~8.5)
#define SMEMB 56576

typedef unsigned int u32;
typedef unsigned short u16;
typedef unsigned long long u64;

typedef __attribute__((ext_vector_type(8))) short bf16x8;
typedef __attribute__((ext_vector_type(4))) float f32x4;

__device__ __forceinline__ float b2f(u16 u) { return __uint_as_float(((u32)u) << 16); }
__device__ __forceinline__ u16 f2b(float x) {
  u32 u = __float_as_uint(x);
  u32 r = ((u >> 16) & 1u) + 0x7FFFu;
  return (u16)((u + r) >> 16);
}
__device__ __forceinline__ u32 umin2(u32 a, u32 b) { return a < b ? a : b; }

#if defined(__has_builtin)
#if __has_builtin(__builtin_amdgcn_global_load_lds)
#define HAVE_GLL 1
#endif
#endif

__device__ __forceinline__ void stage16(const u16* g, u16* l) {
#ifdef HAVE_GLL
  __builtin_amdgcn_global_load_lds((const __attribute__((address_space(1))) void*)g,
                                   (__attribute__((address_space(3))) void*)l, 16, 0, 0);
#else
  *(uint4*)l = *(const uint4*)g;
#endif
}

__device__ __forceinline__ void cvt8(const float* sp, u16* dp) {
  float4 a = *(const float4*)(sp);
  float4 b = *(const float4*)(sp + 4);
  uint4 o;
  o.x = (u32)f2b(a.x) | ((u32)f2b(a.y) << 16);
  o.y = (u32)f2b(a.z) | ((u32)f2b(a.w) << 16);
  o.z = (u32)f2b(b.x) | ((u32)f2b(b.y) << 16);
  o.w = (u32)f2b(b.z) | ((u32)f2b(b.w) << 16);
  *(uint4*)(dp) = o;
}

__device__ __forceinline__ u32 wave_append(u32* cnt, bool pred) {
  u64 mask = __ballot(pred);
  u32 ret = 0xFFFFFFFFu;
  if (pred) {
    int lane = (int)(threadIdx.x & 63);
    int leader = __ffsll((u64)mask) - 1;
    u32 base = 0;
    if (lane == leader) base = atomicAdd(cnt, (u32)__popcll(mask));
    base = __shfl(base, leader, 64);
    ret = base + (u32)__popcll(mask & ((1ull << lane) - 1ull));
  }
  return ret;
}

// 1024-thread inclusive scan; total in tmp[31]
__device__ __forceinline__ u32 scanN(u32 v, u32* tmp, int tid) {
  u32 x = v;
#pragma unroll
  for (int off = 1; off < 64; off <<= 1) {
    u32 y = (u32)__shfl_up((int)x, off, 64);
    if ((tid & 63) >= off) x += y;
  }
  if ((tid & 63) == 63) tmp[tid >> 6] = x;
  __syncthreads();
  if (tid < 64) {
    u32 t = (tid < 16) ? tmp[tid] : 0u;
#pragma unroll
    for (int off = 1; off < 16; off <<= 1) {
      u32 y = (u32)__shfl_up((int)t, off, 64);
      if (tid >= off) t += y;
    }
    if (tid < 16) tmp[tid + 16] = t;
  }
  __syncthreads();
  u32 base = (tid >= 64) ? tmp[16 + (tid >> 6) - 1] : 0u;
  return base + x;
}

__device__ __forceinline__ float redsum1024(float v, float* tmp, int tid) {
#pragma unroll
  for (int off = 32; off > 0; off >>= 1) v += __shfl_xor(v, off, 64);
  if ((tid & 63) == 0) tmp[tid >> 6] = v;
  __syncthreads();
  if (tid < 64) {
    float t = (tid < 16) ? tmp[tid] : 0.f;
#pragma unroll
    for (int off = 8; off > 0; off >>= 1) t += __shfl_xor(t, off, 64);
    if (tid == 0) tmp[0] = t;
  }
  __syncthreads();
  float r = tmp[0];
  __syncthreads();
  return r;
}

__device__ __forceinline__ int binof(float v, float lo, float scale) {
  int b = (int)((v - lo) * scale);
  return b < 0 ? 0 : (b > 2047 ? 2047 : b);
}

__device__ float dotm(const float* f_l, const u16* brow) {
  float a0 = 0.f, a1 = 0.f, a2 = 0.f, a3 = 0.f;
#pragma unroll 4
  for (int k = 0; k < CH; k += 8) {
    uint4 w = *(const uint4*)(brow + k);
    float4 fa = *(const float4*)(f_l + k);
    float4 fb = *(const float4*)(f_l + k + 4);
    a0 += fa.x * b2f((u16)w.x) + fa.y * b2f((u16)(w.x >> 16));
    a1 += fa.z * b2f((u16)w.y) + fa.w * b2f((u16)(w.y >> 16));
    a2 += fb.x * b2f((u16)w.z) + fb.y * b2f((u16)(w.z >> 16));
    a3 += fb.z * b2f((u16)w.w) + fb.w * b2f((u16)(w.w >> 16));
  }
  return (a0 + a1) + (a2 + a3);
}

// ================= PHASE A: convert+scatter+fB+rfilter+zeroing (block b owns rows 2b,2b+1) =================
__device__ void phaseA(int b, int tid, char* smem,
                       const float* bank, const float* f, const int* enq,
                       const int* label, const float* rnd,
                       u16* bankB, u16* fB, float* grl, u32* grcnt,
                       u32* gccnt, float* out) {
  int* enq_l = (int*)smem;            // 512 ints
  int* rowsrc = (int*)(smem + 2048);  // 32 ints
  u32* cnt = (u32*)(smem + 2176);     // 1

  if (tid < 512) enq_l[tid] = enq[tid];
  if (tid == 0) {
    gccnt[2 * b] = 0;
    gccnt[2 * b + 1] = 0;
    if (b == 0) out[0] = 0.0f;
  }
  if (tid < 64) {
    int nr = 2 * b + (tid >> 5);
    int ch = (tid & 31) * 8;
    cvt8(f + (size_t)nr * CH + ch, fB + (size_t)nr * CH + ch);
  }
  __syncthreads();

  // bank conversion: 1283 groups-of-4 (8 rows each), strided by 256 blocks
  const int q = tid >> 8, u = tid & 255;
  for (int g4 = b; g4 < 1283; g4 += 256) {
    if (tid < 32) rowsrc[tid] = -1;
    __syncthreads();
    if (tid < 512) {
      int rel = enq_l[tid] - g4 * 32;
      if (rel >= 0 && rel < 32) atomicMax(&rowsrc[rel], tid);  // last-write-wins = max n
    }
    __syncthreads();
    int g = g4 * 4 + q;
    if (g < 5130) {
      int sub = u >> 5, ch = (u & 31) * 8;
      int row = g * 8 + sub;
      int src = rowsrc[q * 8 + sub];
      const float* sp = (src >= 0) ? (f + (size_t)src * CH + ch)
                                   : (bank + (size_t)row * CH + ch);
      cvt8(sp, bankB + (size_t)row * CH + ch);
    }
    __syncthreads();
  }

  // rfilter rows 2b, 2b+1 (1024 thr x 8 x 5 = 40960 + 80 tail)
  for (int rp = 0; rp < 2; rp++) {
    int n = 2 * b + rp;
    if (tid == 0) cnt[0] = 0;
    __syncthreads();
    const float* rrow = rnd + (size_t)n * ROWS;
    const int lab = label[n];
    float* outbase = grl + (size_t)n * CAPRL * 2;
    int rb = (tid * 8) % 60;
    for (int it = 0; it < 5; it++) {
      int m8 = (it * 1024 + tid) * 8;
      float4 a = *(const float4*)(rrow + m8);
      float4 bb = *(const float4*)(rrow + m8 + 4);
      float rs[8] = {a.x, a.y, a.z, a.w, bb.x, bb.y, bb.z, bb.w};
      int r = rb;
#pragma unroll
      for (int j = 0; j < 8; j++) {
        bool pred = (r != lab) && (rs[j] < T0F);
        u32 slot = wave_append(cnt, pred);
        if (pred && slot < CAPRL) {
          float2 p;
          p.x = rs[j];
          p.y = __uint_as_float((u32)(m8 + j));
          *(float2*)(outbase + slot * 2) = p;
        }
        r++;
        if (r == 60) r = 0;
      }
      rb += 32;  // 8192 % 60
      if (rb >= 60) rb -= 60;
    }
    if (tid < 80) {
      int m = 40960 + tid;
      int r = 40 + tid;
      if (r >= 60) r -= 60;
      float rv = rrow[m];
      bool pred = (r != lab) && (rv < T0F);
      u32 slot = wave_append(cnt, pred);
      if (pred && slot < CAPRL) {
        float2 p;
        p.x = rv;
        p.y = __uint_as_float((u32)m);
        *(float2*)(outbase + slot * 2) = p;
      }
    }
    __syncthreads();
    if (tid == 0) grcnt[n] = cnt[0];
    __syncthreads();
  }
}

// ================= PHASE B: MFMA GEMM tiles striped over 256 blocks =================
__device__ void phaseB(int b, int tid, char* smem,
                       const u16* fB, const u16* bankB, const int* label,
                       float* gclist, u32* gccnt, u16* gpos) {
  u16* As = (u16*)smem;                    // 128x32 u16 = 8KB
  u16* Bs = (u16*)(smem + 8192);           // 8KB
  float* cstage = (float*)(smem + 16384);  // 128*32*4 = 16KB
  u32* ccnt_l = (u32*)(smem + 32768);      // 128
  int* lab_l = (int*)(smem + 33280);       // 128

  const int wave = tid >> 6, lane = tid & 63;
  const int wm = (wave & 1) * 64;   // 2 wave-rows x 64
  const int wn = (wave >> 1) * 16;  // 8 wave-cols x 16
  const int m_in = lane & 15;
  const int ks = (lane >> 4) * 8;
  const int rr = (lane >> 4) * 4;
  const int cc = lane & 15;
  const int su = (tid < 512) ? tid : tid - 512;
  const int srow = su >> 2;
  const int skk = (su & 3) * 8;

  for (int t = b; t < 1284; t += 256) {
    const int bm = (t & 3) * 128;
    const int bn = (t >> 2) * 128;
    __syncthreads();
    if (tid < 128) { ccnt_l[tid] = 0; lab_l[tid] = label[bm + tid]; }

    f32x4 acc[4] = {};
    for (int k0 = 0; k0 < CH; k0 += 32) {
      __syncthreads();
      if (tid < 512) {
        stage16(fB + (size_t)(bm + srow) * CH + k0 + skk, As + su * 8);
      } else {
        int rbq = bn + srow;
        if (rbq >= ROWS) rbq = bn;
        stage16(bankB + (size_t)rbq * CH + k0 + skk, Bs + su * 8);
      }
      __syncthreads();
      bf16x8 af[4], bfr;
#pragma unroll
      for (int mi = 0; mi < 4; mi++)
        af[mi] = *(const bf16x8*)(As + (wm + mi * 16 + m_in) * 32 + ks);
      bfr = *(const bf16x8*)(Bs + (wn + m_in) * 32 + ks);
#pragma unroll
      for (int mi = 0; mi < 4; mi++)
        acc[mi] = __builtin_amdgcn_mfma_f32_16x16x32_bf16(af[mi], bfr, acc[mi], 0, 0, 0);
    }

    int ncol = bn + wn + cc;
    bool colok = (ncol < ROWS);
    int jdiv = 0, ncolmod = 0;
    if (colok) { jdiv = ncol / 60; ncolmod = ncol - jdiv * 60; }
#pragma unroll
    for (int mi = 0; mi < 4; mi++) {
      int rloc = wm + mi * 16 + rr;
#pragma unroll
      for (int qq = 0; qq < 4; qq++) {
        if (colok) {
          int rq = rloc + qq;
          u16 cw = f2b(acc[mi][qq]);
          float c = b2f(cw);
          if (ncolmod == lab_l[rq]) {
            gpos[(size_t)(bm + rq) * MEM + jdiv] = cw;
          } else if (c > T1F) {
            u32 slot = atomicAdd(&ccnt_l[rq], 1u);
            if (slot < CSTG) {
              cstage[rq * CSTG + slot] = c;
            } else {  // near-impossible spill, still exact
              int grow = bm + rq;
              u32 s2 = atomicAdd(&gccnt[grow], 1u);
              if (s2 < CAPCL) gclist[(size_t)grow * CAPCL + s2] = c;
            }
          }
        }
      }
    }
    __syncthreads();
    if (tid < 128) {
      u32 k = umin2(ccnt_l[tid], CSTG);
      if (k) {
        int grow = bm + tid;
        u32 base = atomicAdd(&gccnt[grow], k);
        for (u32 i = 0; i < k; i++) {
          u32 s = base + i;
          if (s < CAPCL) gclist[(size_t)grow * CAPCL + s] = cstage[tid * CSTG + i];
        }
      }
    }
  }
}

// ================= PHASE C: per-row selection + loss =================
__device__ void phaseC(int n, int tid, char* smem,
                       const int* label, const float* gclist, const u32* gccnt,
                       const float* grl, const u32* grcnt, const u16* gpos,
                       const u16* fB, const u16* bankB, const float* rnd,
                       float* out) {
  const int lab = label[n];
  u32* histc = (u32*)(smem);               // 2048
  u32* histr = (u32*)(smem + 8192);        // 2048
  float* cl = (float*)(smem + 16384);      // 4096 (posv aliases)
  float* rl_rv = (float*)(smem + 32768);   // 2048
  u32* rl_mi = (u32*)(smem + 40960);       // 2048
  u32* wl = (u32*)(smem + 49152);          // 512
  float* cb_c = (float*)(smem + 51200);    // 512
  float* rb_r = (float*)(smem + 53248);    // 256
  u32* rb_m = (u32*)(smem + 54272);        // 256
  float* f_l = (float*)(smem + 55296);     // 256
  u32* stmp = (u32*)(smem + 56320);        // 32
  float* fred = (float*)(smem + 56448);    // 16
  u32* ctl = (u32*)(smem + 56512);         // 16
  float* bcf = (float*)(ctl + 8);
  float* posv = cl;

  __syncthreads();
  const u32 Fg = gccnt[n];
  const u32 Gg = grcnt[n];
  const bool cok = (Fg >= NEGN && Fg <= CAPCL);
  const bool rok = (Gg >= NEGN && Gg <= CAPRL);
  const float T1e = cok ? T1F : -1.1f;
  const float sc_c = 2048.0f / (cok ? (1.0625f - T1F) : 2.2f);
  const float sc_r = 2048.0f / (rok ? T0F : 1.0625f);

  for (int i = tid; i < 2048; i += 1024) { histc[i] = 0; histr[i] = 0; }
  if (tid < 16) ctl[tid] = 0;
  if (tid < 256) f_l[tid] = b2f(fB[(size_t)n * CH + tid]);
  __syncthreads();

  if (cok) {
    for (u32 i = tid; i < Fg; i += 1024) {
      float c = gclist[(size_t)n * CAPCL + i];
      cl[i] = c;
      atomicAdd(&histc[binof(c, T1e, sc_c)], 1u);
    }
  } else {
    for (int m = tid; m < ROWS; m += 1024) {
      if (m % 60 == lab) continue;
      float c = b2f(f2b(dotm(f_l, bankB + (size_t)m * CH)));
      atomicAdd(&histc[binof(c, T1e, sc_c)], 1u);
    }
  }
  if (rok) {
    const float* rbase = grl + (size_t)n * CAPRL * 2;
    for (u32 i = tid; i < Gg; i += 1024) {
      float2 p = *(const float2*)(rbase + i * 2);
      rl_rv[i] = p.x;
      rl_mi[i] = __float_as_uint(p.y);
      atomicAdd(&histr[binof(p.x, 0.0f, sc_r)], 1u);
    }
  } else {
    const float* rrow = rnd + (size_t)n * ROWS;
    for (int m = tid; m < ROWS; m += 1024) {
      if (m % 60 == lab) continue;
      atomicAdd(&histr[binof(rrow[m], 0.0f, sc_r)], 1u);
    }
  }
  __syncthreads();

  u32 fsum = histc[tid * 2] + histc[tid * 2 + 1];
  u32 finc = scanN(fsum, stmp, tid);
  u32 F = stmp[31];
  u32 fexc = finc - fsum;
  u32 tcpos = F - NEGN + 1;
  if (fexc < tcpos && tcpos <= finc) {
    u32 run = fexc;
#pragma unroll
    for (int i = 0; i < 2; i++) {
      u32 h = histc[tid * 2 + i];
      if (run + h >= tcpos) { ctl[2] = (u32)(tid * 2 + i); ctl[3] = F - (run + h); break; }
      run += h;
    }
  }
  u32 gsum = histr[tid * 2] + histr[tid * 2 + 1];
  u32 ginc = scanN(gsum, stmp, tid);
  u32 gexc = ginc - gsum;
  if (gexc < NEGN && NEGN <= ginc) {
    u32 run = gexc;
#pragma unroll
    for (int i = 0; i < 2; i++) {
      u32 h = histr[tid * 2 + i];
      if (run + h >= NEGN) { ctl[4] = (u32)(tid * 2 + i); ctl[5] = run; break; }
      run += h;
    }
  }
  __syncthreads();
  const u32 b_c = ctl[2], cnt_gt = ctl[3];
  const u32 b_r = ctl[4], cnt_lt = ctl[5];
  const u32 need_c = NEGN - cnt_gt;
  const u32 need_r = NEGN - cnt_lt;

  float sH = 0.f;
  if (cok) {
    for (u32 i = tid; i < Fg; i += 1024) {
      float c = cl[i];
      u32 bb = (u32)binof(c, T1e, sc_c);
      if (bb > b_c) sH += expf(c);
      else if (bb == b_c) {
        u32 id = atomicAdd(&ctl[0], 1u);
        if (id < 512) cb_c[id] = c;
      }
    }
  } else {
    for (int m = tid; m < ROWS; m += 1024) {
      if (m % 60 == lab) continue;
      float c = b2f(f2b(dotm(f_l, bankB + (size_t)m * CH)));
      u32 bb = (u32)binof(c, T1e, sc_c);
      if (bb > b_c) sH += expf(c);
      else if (bb == b_c) {
        u32 id = atomicAdd(&ctl[0], 1u);
        if (id < 512) cb_c[id] = c;
      }
    }
  }
  if (rok) {
    for (u32 i = tid; i < Gg; i += 1024) {
      float rv = rl_rv[i];
      u32 bb = (u32)binof(rv, 0.0f, sc_r);
      if (bb < b_r) {
        u32 id = atomicAdd(&ctl[6], 1u);
        wl[id] = rl_mi[i];  // id < cnt_lt <= 511
      } else if (bb == b_r) {
        u32 id = atomicAdd(&ctl[1], 1u);
        if (id < 256) { rb_r[id] = rv; rb_m[id] = rl_mi[i]; }
      }
    }
  } else {
    const float* rrow = rnd + (size_t)n * ROWS;
    for (int m = tid; m < ROWS; m += 1024) {
      if (m % 60 == lab) continue;
      float rv = rrow[m];
      u32 bb = (u32)binof(rv, 0.0f, sc_r);
      if (bb < b_r) {
        u32 id = atomicAdd(&ctl[6], 1u);
        if (id < 512) wl[id] = (u32)m;
      } else if (bb == b_r) {
        u32 id = atomicAdd(&ctl[1], 1u);
        if (id < 256) { rb_r[id] = rv; rb_m[id] = (u32)m; }
      }
    }
  }
  __syncthreads();
  float SHsum = redsum1024(sH, fred, tid);

  if (tid == 0) {
    float addH = 0.f;
    u32 Lc = umin2(ctl[0], 512u);
    u32 kc = umin2(need_c, Lc);
    for (u32 k = 0; k < kc; k++) {
      int best = 0;
      float bv = -3.0e38f;
      for (u32 i = 0; i < Lc; i++)
        if (cb_c[i] > bv) { bv = cb_c[i]; best = (int)i; }
      cb_c[best] = -3.0e38f;
      addH += expf(bv);
    }
    bcf[0] = addH;
    // rand boundary bin: stable (rand, index) ascending; append winners
    u32 Lr = umin2(ctl[1], 256u);
    for (u32 i = 1; i < Lr; i++) {
      float rv = rb_r[i]; u32 mm = rb_m[i];
      int j = (int)i - 1;
      while (j >= 0 && (rb_r[j] > rv || (rb_r[j] == rv && rb_m[j] > mm))) {
        rb_r[j + 1] = rb_r[j]; rb_m[j + 1] = rb_m[j];
        j--;
      }
      rb_r[j + 1] = rv; rb_m[j + 1] = mm;
    }
    u32 kr = umin2(need_r, Lr);
    u32 base = ctl[6];
    for (u32 i = 0; i < kr; i++)
      if (base + i < 512) wl[base + i] = rb_m[i];
    ctl[7] = umin2(base + kr, 512u);
  }
  __syncthreads();

  // winner dots -> S_R: 8 lanes per winner, shfl-reduced
  float sR = 0.f;
  {
    u32 W = ctl[7];
    int w8 = tid >> 3;
    int p = tid & 7;
    const float* flp = f_l + p * 32;
    for (u32 base = 0; base < W; base += 128) {
      u32 wi = base + (u32)w8;
      float part = 0.f;
      if (wi < W) {
        const u16* brow = bankB + (size_t)wl[wi] * CH + p * 32;
#pragma unroll
        for (int k = 0; k < 32; k += 8) {
          uint4 wv = *(const uint4*)(brow + k);
          float4 fa = *(const float4*)(flp + k);
          float4 fb2 = *(const float4*)(flp + k + 4);
          part += fa.x * b2f((u16)wv.x) + fa.y * b2f((u16)(wv.x >> 16))
                + fa.z * b2f((u16)wv.y) + fa.w * b2f((u16)(wv.y >> 16))
                + fb2.x * b2f((u16)wv.z) + fb2.y * b2f((u16)(wv.z >> 16))
                + fb2.z * b2f((u16)wv.w) + fb2.w * b2f((u16)(wv.w >> 16));
        }
      }
      part += __shfl_xor(part, 1, 64);
      part += __shfl_xor(part, 2, 64);
      part += __shfl_xor(part, 4, 64);
      if (p == 0 && wi < W) sR += expf(b2f(f2b(part)));
    }
  }
  float SRsum = redsum1024(sR, fred, tid);
  const float S_H = SHsum + bcf[0];
  const float S_R = SRsum;
  __syncthreads();  // cl reads done before posv alias overwrite

  // positives: 684 from gpos, 128 smallest via bitonic (1 elem/thread)
  float v = (tid < MEM) ? b2f(gpos[(size_t)n * MEM + tid]) : INFINITY;
  for (u32 k = 2; k <= 1024; k <<= 1) {
    for (u32 j = k >> 1; j > 0; j >>= 1) {
      float pv;
      if (j >= 64) {
        posv[tid] = v;
        __syncthreads();
        pv = posv[tid ^ j];
        __syncthreads();
      } else {
        pv = __shfl_xor(v, (int)j, 64);
      }
      bool up = (((u32)tid & k) == 0);
      bool lower = (((u32)tid & j) == 0);
      float mn = fminf(v, pv), mx = fmaxf(v, pv);
      v = (lower == up) ? mn : mx;
    }
  }

  float term = 0.f;
  if (tid < POSN) {
    float p = v;
    float e = expf(p);
    term = (p - logf(e + S_H)) + (p - logf(e + S_R));
  }
  float tot = redsum1024(term, fred, tid);
  if (tid == 0) atomicAdd(out, -tot / (float)(BATCHN * 2 * POSN));
  __syncthreads();
}

// ================= kernels =================
__global__ __launch_bounds__(1024, 4) void k_fused(
    const float* __restrict__ bank, const float* __restrict__ f,
    const int* __restrict__ enq, const int* __restrict__ label,
    const float* __restrict__ rnd,
    u16* __restrict__ bankB, u16* __restrict__ fB,
    float* __restrict__ grl, u32* __restrict__ grcnt,
    float* __restrict__ gclist, u32* __restrict__ gccnt,
    u16* __restrict__ gpos, float* __restrict__ out) {
  cg::grid_group grid = cg::this_grid();
  __shared__ __align__(16) char smem[SMEMB];
  const int b = blockIdx.x, tid = threadIdx.x;
  phaseA(b, tid, smem, bank, f, enq, label, rnd, bankB, fB, grl, grcnt, gccnt, out);
  __threadfence();
  grid.sync();
  phaseB(b, tid, smem, fB, bankB, label, gclist, gccnt, gpos);
  __threadfence();
  grid.sync();
  phaseC(2 * b, tid, smem, label, gclist, gccnt, grl, grcnt, gpos, fB, bankB, rnd, out);
  phaseC(2 * b + 1, tid, smem, label, gclist, gccnt, grl, grcnt, gpos, fB, bankB, rnd, out);
}

__global__ __launch_bounds__(1024, 4) void k_pA(
    const float* __restrict__ bank, const float* __restrict__ f,
    const int* __restrict__ enq, const int* __restrict__ label,
    const float* __restrict__ rnd, u16* __restrict__ bankB, u16* __restrict__ fB,
    float* __restrict__ grl, u32* __restrict__ grcnt, u32* __restrict__ gccnt,
    float* __restrict__ out) {
  __shared__ __align__(16) char smem[SMEMB];
  phaseA(blockIdx.x, threadIdx.x, smem, bank, f, enq, label, rnd, bankB, fB, grl, grcnt, gccnt, out);
}

__global__ __launch_bounds__(1024, 4) void k_pB(
    const u16* __restrict__ fB, const u16* __restrict__ bankB,
    const int* __restrict__ label, float* __restrict__ gclist,
    u32* __restrict__ gccnt, u16* __restrict__ gpos) {
  __shared__ __align__(16) char smem[SMEMB];
  phaseB(blockIdx.x, threadIdx.x, smem, fB, bankB, label, gclist, gccnt, gpos);
}

__global__ __launch_bounds__(1024, 4) void k_pC(
    const int* __restrict__ label, const float* __restrict__ gclist,
    const u32* __restrict__ gccnt, const float* __restrict__ grl,
    const u32* __restrict__ grcnt, const u16* __restrict__ gpos,
    const u16* __restrict__ fB, const u16* __restrict__ bankB,
    const float* __restrict__ rnd, float* __restrict__ out) {
  __shared__ __align__(16) char smem[SMEMB];
  phaseC(2 * blockIdx.x, threadIdx.x, smem, label, gclist, gccnt, grl, grcnt, gpos, fB, bankB, rnd, out);
  phaseC(2 * blockIdx.x + 1, threadIdx.x, smem, label, gclist, gccnt, grl, grcnt, gpos, fB, bankB, rnd, out);
}

extern "C" void kernel_launch(void* const* d_in, const int* in_sizes, int n_in,
                              void* d_out, int out_size, void* d_ws, size_t ws_size,
                              hipStream_t stream) {
  const float* f = (const float*)d_in[0];
  const int* label = (const int*)d_in[1];
  const int* enq = (const int*)d_in[2];
  const float* bank = (const float*)d_in[3];
  const float* rnd = (const float*)d_in[5];
  float* out = (float*)d_out;

  char* ws = (char*)d_ws;
  u16* bankB = (u16*)ws;                        // 21,012,480
  u16* fB = (u16*)(ws + 21012480);              //    262,144
  float* gclist = (float*)(ws + 21274624);      // 8,388,608
  float* grl = (float*)(ws + 29663232);         // 8,388,608
  u16* gpos = (u16*)(ws + 38051840);            //   700,416
  u32* gccnt = (u32*)(ws + 38752256);           // 2048
  u32* grcnt = (u32*)(ws + 38754304);           // 2048

  void* args[] = {(void*)&bank, (void*)&f, (void*)&enq, (void*)&label, (void*)&rnd,
                  (void*)&bankB, (void*)&fB, (void*)&grl, (void*)&grcnt,
                  (void*)&gclist, (void*)&gccnt, (void*)&gpos, (void*)&out};
  hipError_t err = hipLaunchCooperativeKernel((void*)k_fused, dim3(256), dim3(1024),
                                              args, 0, stream);
  if (err != hipSuccess) {
    // deterministic fallback: same phase functions as 3 stream-ordered launches
    k_pA<<<dim3(256), dim3(1024), 0, stream>>>(bank, f, enq, label, rnd, bankB, fB,
                                               grl, grcnt, gccnt, out);
    k_pB<<<dim3(256), dim3(1024), 0, stream>>>(fB, bankB, label, gclist, gccnt, gpos);
    k_pC<<<dim3(256), dim3(1024), 0, stream>>>(label, gclist, gccnt, grl, grcnt, gpos,
                                               fB, bankB, rnd, out);
  }
}